// Round 5
// baseline (1053.865 us; speedup 1.0000x reference)
//
#include <hip/hip_runtime.h>
#include <hip/hip_cooperative_groups.h>

namespace cg = cooperative_groups;

#define NN 10000
#define EE 320000
#define ET (EE + NN)      // 330000 edges incl self-loops
#define FIN 256
#define HD 128
#define NEG 0.2f
#define GB1 625           // gemm tiles (NN/16)
#define NTHR 256

// Inputs fp32, edge_index int32, OUTPUT fp32.

struct MegaP {
    const float *x, *W1, *as1, *ad1, *b1, *W2, *as2, *ad2, *b2, *Wr, *br, *Wc, *bc;
    const int *ei;
    float *h, *g1, *a_s, *a_d, *r, *out;
    int *counts, *offsets, *rank, *srclist;
};

__device__ __forceinline__ float edge_w(float as_v, float adn) {
    float e = as_v + adn;
    e = (e > 0.f) ? e : NEG * e;
    return __expf(e);
}

// ---- gemm tile body: 16 nodes x KK -> HD, 256 threads (4 node-groups x 64 lanes) ----
template<int KK>
__device__ __forceinline__ void gemm_body(const float* __restrict__ xin,
        const float* __restrict__ W,
        const float* __restrict__ atts, const float* __restrict__ attd,
        float* __restrict__ h, float* __restrict__ a_s, float* __restrict__ a_d,
        float* smem, int tile, int t) {
    int m0 = tile * 16;
    const float4* xv = (const float4*)(xin + (size_t)m0 * KK);
    float4* xsv = (float4*)smem;
    #pragma unroll
    for (int i = 0; i < KK / 64; i++)          // 16*KK/4 float4 / 256 threads
        xsv[t + 256 * i] = xv[t + 256 * i];
    __syncthreads();

    int g = t >> 6, tt = t & 63, f = tt * 2;
    const float* xg = smem + g * 4 * KK;
    float2 acc[4];
    #pragma unroll
    for (int m = 0; m < 4; m++) acc[m] = make_float2(0.f, 0.f);

    for (int k = 0; k < KK; k += 4) {
        float2 w0 = *(const float2*)&W[(k + 0) * HD + f];
        float2 w1 = *(const float2*)&W[(k + 1) * HD + f];
        float2 w2 = *(const float2*)&W[(k + 2) * HD + f];
        float2 w3 = *(const float2*)&W[(k + 3) * HD + f];
        #pragma unroll
        for (int m = 0; m < 4; m++) {
            float4 xk = *(const float4*)&xg[m * KK + k];
            acc[m].x += xk.x * w0.x; acc[m].y += xk.x * w0.y;
            acc[m].x += xk.y * w1.x; acc[m].y += xk.y * w1.y;
            acc[m].x += xk.z * w2.x; acc[m].y += xk.z * w2.y;
            acc[m].x += xk.w * w3.x; acc[m].y += xk.w * w3.y;
        }
    }

    float2 ats = *(const float2*)&atts[f];
    float2 atd = *(const float2*)&attd[f];
    #pragma unroll
    for (int m = 0; m < 4; m++) {
        int node = m0 + g * 4 + m;
        *(float2*)&h[(size_t)node * HD + f] = acc[m];
        float vs = acc[m].x * ats.x + acc[m].y * ats.y;
        float vd = acc[m].x * atd.x + acc[m].y * atd.y;
        #pragma unroll
        for (int off = 32; off > 0; off >>= 1) {
            vs += __shfl_down(vs, off);
            vd += __shfl_down(vd, off);
        }
        if (tt == 0) { a_s[node] = vs; a_d[node] = vd; }
    }
    __syncthreads();   // smem safe for next tile / phase
}

// ---- agg body: 2 nodes per block per iter; per node 4 slots x 32 lanes (proven) ----
template<bool DOWR>
__device__ __forceinline__ void agg_body(const MegaP& P, const float* __restrict__ bias,
        float* __restrict__ outv /* g1 or r */, float* smem, int bid, int nb, int t) {
    const float4* h4 = (const float4*)P.h;
    float* accs = smem;                 // [2][4][HD] = 1024 floats
    float* zsh  = smem + 8 * HD;        // [2][4]
    float* red  = smem + 8 * HD + 8;    // [4]
    int half = t >> 7;
    int tt = t & 127;
    int slot = tt >> 5, q = tt & 31;
    for (int base = bid * 2; base < NN; base += nb * 2) {
        int node = base + half;         // NN even, base+1 <= 9999
        int beg = P.offsets[node], end = P.offsets[node + 1];
        float adn = P.a_d[node];
        float4 acc = make_float4(0.f, 0.f, 0.f, 0.f);
        float z = 0.f;
        int p = beg + slot;
        for (; p + 4 < end; p += 8) {
            int s0 = P.srclist[p];
            int s1 = P.srclist[p + 4];
            float4 h0 = h4[(size_t)s0 * 32 + q];
            float4 h1 = h4[(size_t)s1 * 32 + q];
            float w0 = edge_w(P.a_s[s0], adn);
            float w1 = edge_w(P.a_s[s1], adn);
            z += w0 + w1;
            acc.x += w0 * h0.x + w1 * h1.x;
            acc.y += w0 * h0.y + w1 * h1.y;
            acc.z += w0 * h0.z + w1 * h1.z;
            acc.w += w0 * h0.w + w1 * h1.w;
        }
        if (p < end) {
            int s0 = P.srclist[p];
            float4 h0 = h4[(size_t)s0 * 32 + q];
            float w0 = edge_w(P.a_s[s0], adn);
            z += w0;
            acc.x += w0 * h0.x; acc.y += w0 * h0.y;
            acc.z += w0 * h0.z; acc.w += w0 * h0.w;
        }
        *(float4*)&accs[(half * 4 + slot) * HD + q * 4] = acc;
        if (q == 0) zsh[half * 4 + slot] = z;
        __syncthreads();
        float v = accs[(half * 4 + 0) * HD + tt] + accs[(half * 4 + 1) * HD + tt]
                + accs[(half * 4 + 2) * HD + tt] + accs[(half * 4 + 3) * HD + tt];
        float zz = zsh[half * 4 + 0] + zsh[half * 4 + 1]
                 + zsh[half * 4 + 2] + zsh[half * 4 + 3];
        float o = v / zz + bias[tt];
        o = (o > 0.f) ? o : 0.f;
        if (!DOWR) {
            outv[(size_t)node * HD + tt] = o;
        } else {
            float part = o * P.Wr[tt];
            #pragma unroll
            for (int off = 32; off > 0; off >>= 1) part += __shfl_down(part, off);
            if ((t & 63) == 0) red[t >> 6] = part;
            __syncthreads();
            if (tt == 0) outv[node] = red[half * 2] + red[half * 2 + 1] + P.br[0];
        }
        __syncthreads();   // protect accs/red before next iteration overwrites
    }
}

// ---- the mega-kernel: whole pipeline, 7 grid syncs ----

__global__ __launch_bounds__(NTHR, 4) void k_mega(MegaP P) {
    cg::grid_group grid = cg::this_grid();
    __shared__ float smem[16 * FIN];   // 16 KB, reused per phase
    int t = threadIdx.x, bid = blockIdx.x, nb = gridDim.x;

    // P0: zero counts
    for (int i = bid * NTHR + t; i < NN; i += nb * NTHR) P.counts[i] = 0;
    grid.sync();

    // P1: gemm1 (front blocks, grid-stride over 625 tiles) || hist+rank (rest)
    int gemmB = (nb >= GB1 + 64) ? GB1 : (nb * 5) / 8;
    if (bid < gemmB) {
        for (int tile = bid; tile < GB1; tile += gemmB)
            gemm_body<FIN>(P.x, P.W1, P.as1, P.ad1, P.h, P.a_s, P.a_d, smem, tile, t);
    } else {
        int hb = nb - gemmB;
        for (int i = (bid - gemmB) * NTHR + t; i < ET; i += hb * NTHR) {
            int d = (i < EE) ? P.ei[EE + i] : (i - EE);
            P.rank[i] = atomicAdd(&P.counts[d], 1);
        }
    }
    grid.sync();

    // P2: exclusive scan counts -> offsets (block 0, 256 threads, 2-pass reads)
    if (bid == 0) {
        const int CHUNK = 40;   // 256*40 >= 10000
        int* ism = (int*)smem;
        int lane = t & 63, wid = t >> 6;
        int base = t * CHUNK;
        int s = 0;
        for (int i = 0; i < CHUNK; i++) {
            int idx = base + i;
            if (idx < NN) s += P.counts[idx];
        }
        int ps = s;
        #pragma unroll
        for (int off = 1; off < 64; off <<= 1) {
            int v = __shfl_up(ps, off);
            if (lane >= off) ps += v;
        }
        if (lane == 63) ism[wid] = ps;
        __syncthreads();
        int wbase = 0;
        for (int w = 0; w < wid; w++) wbase += ism[w];
        int run = wbase + ps - s;
        for (int i = 0; i < CHUNK; i++) {
            int idx = base + i;
            if (idx < NN) { P.offsets[idx] = run; run += P.counts[idx]; }
        }
        if (t == NTHR - 1) P.offsets[NN] = wbase + ps;
    }
    grid.sync();

    // P3: scatter (atomic-free)
    for (int i = bid * NTHR + t; i < ET; i += nb * NTHR) {
        int s, d;
        if (i < EE) { s = P.ei[i]; d = P.ei[EE + i]; }
        else        { s = i - EE; d = s; }
        P.srclist[P.offsets[d] + P.rank[i]] = s;
    }
    grid.sync();

    // P4: agg1 -> g1 (relu fused)
    agg_body<false>(P, P.b1, P.g1, smem, bid, nb, t);
    grid.sync();

    // P5: gemm2
    if (bid < gemmB) {
        for (int tile = bid; tile < GB1; tile += gemmB)
            gemm_body<HD>(P.g1, P.W2, P.as2, P.ad2, P.h, P.a_s, P.a_d, smem, tile, t);
    }
    grid.sync();

    // P6: agg2 + reduce_dim -> r
    agg_body<true>(P, P.b2, P.r, smem, bid, nb, t);
    grid.sync();

    // P7: classifier (block 0)
    if (bid == 0) {
        float c0 = 0.f, c1 = 0.f;
        for (int n = t; n < NN; n += NTHR) {
            float rv = P.r[n];
            c0 += rv * P.Wc[2 * n];
            c1 += rv * P.Wc[2 * n + 1];
        }
        #pragma unroll
        for (int off = 32; off > 0; off >>= 1) {
            c0 += __shfl_down(c0, off);
            c1 += __shfl_down(c1, off);
        }
        float* red0 = smem; float* red1 = smem + 4;
        if ((t & 63) == 0) { red0[t >> 6] = c0; red1[t >> 6] = c1; }
        __syncthreads();
        if (t == 0) {
            P.out[0] = red0[0] + red0[1] + red0[2] + red0[3] + P.bc[0];
            P.out[1] = red1[0] + red1[1] + red1[2] + red1[3] + P.bc[1];
        }
    }
}

// ================= fallback: proven round-4 multi-kernel path =================

__global__ __launch_bounds__(256) void k_gemm1_hist(
        const float* __restrict__ x, const float* __restrict__ W,
        const float* __restrict__ atts, const float* __restrict__ attd,
        float* __restrict__ h, float* __restrict__ a_s, float* __restrict__ a_d,
        const int* __restrict__ ei, int* __restrict__ counts, int* __restrict__ rank) {
    __shared__ float xs[16 * FIN];
    int t = threadIdx.x;
    if (blockIdx.x >= GB1) {
        int i = (blockIdx.x - GB1) * 256 + t;
        if (i < ET) {
            int d = (i < EE) ? ei[EE + i] : (i - EE);
            rank[i] = atomicAdd(&counts[d], 1);
        }
        return;
    }
    gemm_body<FIN>(x, W, atts, attd, h, a_s, a_d, xs, blockIdx.x, t);
}

__global__ __launch_bounds__(1024) void k_scan(const int* __restrict__ counts,
                                               int* __restrict__ offsets) {
    const int CHUNK = 10;
    __shared__ int wsum[16];
    int t = threadIdx.x, lane = t & 63, wid = t >> 6;
    int base = t * CHUNK;
    int c[CHUNK];
    int s = 0;
    #pragma unroll
    for (int i = 0; i < CHUNK; i++) {
        int idx = base + i;
        c[i] = (idx < NN) ? counts[idx] : 0;
        s += c[i];
    }
    int ps = s;
    #pragma unroll
    for (int off = 1; off < 64; off <<= 1) {
        int v = __shfl_up(ps, off);
        if (lane >= off) ps += v;
    }
    if (lane == 63) wsum[wid] = ps;
    __syncthreads();
    if (t < 16) {
        int v = wsum[t];
        #pragma unroll
        for (int off = 1; off < 16; off <<= 1) {
            int u = __shfl_up(v, off);
            if (t >= off) v += u;
        }
        wsum[t] = v;
    }
    __syncthreads();
    int wbase = (wid > 0) ? wsum[wid - 1] : 0;
    int run = wbase + ps - s;
    #pragma unroll
    for (int i = 0; i < CHUNK; i++) {
        int idx = base + i;
        if (idx < NN) { offsets[idx] = run; run += c[i]; }
    }
    if (t == 1023) offsets[NN] = wbase + ps;
}

__global__ __launch_bounds__(256) void k_scatter(const int* __restrict__ ei,
                                                 const int* __restrict__ rank,
                                                 const int* __restrict__ offsets,
                                                 int* __restrict__ srclist) {
    int i = blockIdx.x * blockDim.x + threadIdx.x;
    if (i >= ET) return;
    int s, d;
    if (i < EE) { s = ei[i]; d = ei[EE + i]; }
    else        { s = i - EE; d = s; }
    srclist[offsets[d] + rank[i]] = s;
}

__global__ void k_agg1(const int* __restrict__ offsets, const int* __restrict__ srclist,
                       const float* __restrict__ a_s, const float* __restrict__ a_d,
                       const float4* __restrict__ h4, const float* __restrict__ bias,
                       float* __restrict__ g) {
    __shared__ float accs[4][HD];
    __shared__ float zs[4];
    int node = blockIdx.x, t = threadIdx.x;
    int slot = t >> 5, q = t & 31;
    int beg = offsets[node], end = offsets[node + 1];
    float adn = a_d[node];
    float4 acc = make_float4(0.f, 0.f, 0.f, 0.f);
    float z = 0.f;
    int p = beg + slot;
    for (; p + 4 < end; p += 8) {
        int s0 = srclist[p];
        int s1 = srclist[p + 4];
        float4 h0 = h4[(size_t)s0 * 32 + q];
        float4 h1 = h4[(size_t)s1 * 32 + q];
        float w0 = edge_w(a_s[s0], adn);
        float w1 = edge_w(a_s[s1], adn);
        z += w0 + w1;
        acc.x += w0 * h0.x + w1 * h1.x;
        acc.y += w0 * h0.y + w1 * h1.y;
        acc.z += w0 * h0.z + w1 * h1.z;
        acc.w += w0 * h0.w + w1 * h1.w;
    }
    if (p < end) {
        int s0 = srclist[p];
        float4 h0 = h4[(size_t)s0 * 32 + q];
        float w0 = edge_w(a_s[s0], adn);
        z += w0;
        acc.x += w0 * h0.x; acc.y += w0 * h0.y;
        acc.z += w0 * h0.z; acc.w += w0 * h0.w;
    }
    *(float4*)&accs[slot][q * 4] = acc;
    if (q == 0) zs[slot] = z;
    __syncthreads();
    float v = accs[0][t] + accs[1][t] + accs[2][t] + accs[3][t];
    float zz = zs[0] + zs[1] + zs[2] + zs[3];
    float o = v / zz + bias[t];
    g[(size_t)node * HD + t] = (o > 0.f) ? o : 0.f;
}

__global__ __launch_bounds__(256) void k_gemm2(const float* __restrict__ x,
                        const float* __restrict__ W,
                        const float* __restrict__ atts, const float* __restrict__ attd,
                        float* __restrict__ h, float* __restrict__ a_s,
                        float* __restrict__ a_d) {
    __shared__ float xs[16 * HD];
    gemm_body<HD>(x, W, atts, attd, h, a_s, a_d, xs, blockIdx.x, threadIdx.x);
}

__global__ void k_agg2(const int* __restrict__ offsets, const int* __restrict__ srclist,
                       const float* __restrict__ a_s, const float* __restrict__ a_d,
                       const float4* __restrict__ h4, const float* __restrict__ bias,
                       const float* __restrict__ Wr, const float* __restrict__ br,
                       float* __restrict__ r) {
    __shared__ float accs[4][HD];
    __shared__ float zs[4];
    __shared__ float red[2];
    int node = blockIdx.x, t = threadIdx.x;
    int slot = t >> 5, q = t & 31;
    int beg = offsets[node], end = offsets[node + 1];
    float adn = a_d[node];
    float4 acc = make_float4(0.f, 0.f, 0.f, 0.f);
    float z = 0.f;
    int p = beg + slot;
    for (; p + 4 < end; p += 8) {
        int s0 = srclist[p];
        int s1 = srclist[p + 4];
        float4 h0 = h4[(size_t)s0 * 32 + q];
        float4 h1 = h4[(size_t)s1 * 32 + q];
        float w0 = edge_w(a_s[s0], adn);
        float w1 = edge_w(a_s[s1], adn);
        z += w0 + w1;
        acc.x += w0 * h0.x + w1 * h1.x;
        acc.y += w0 * h0.y + w1 * h1.y;
        acc.z += w0 * h0.z + w1 * h1.z;
        acc.w += w0 * h0.w + w1 * h1.w;
    }
    if (p < end) {
        int s0 = srclist[p];
        float4 h0 = h4[(size_t)s0 * 32 + q];
        float w0 = edge_w(a_s[s0], adn);
        z += w0;
        acc.x += w0 * h0.x; acc.y += w0 * h0.y;
        acc.z += w0 * h0.z; acc.w += w0 * h0.w;
    }
    *(float4*)&accs[slot][q * 4] = acc;
    if (q == 0) zs[slot] = z;
    __syncthreads();
    float v = accs[0][t] + accs[1][t] + accs[2][t] + accs[3][t];
    float zz = zs[0] + zs[1] + zs[2] + zs[3];
    float o = v / zz + bias[t];
    o = (o > 0.f) ? o : 0.f;
    float part = o * Wr[t];
    #pragma unroll
    for (int off = 32; off > 0; off >>= 1) part += __shfl_down(part, off);
    if ((t & 63) == 0) red[t >> 6] = part;
    __syncthreads();
    if (t == 0) r[node] = red[0] + red[1] + br[0];
}

__global__ __launch_bounds__(1024) void k_cls(const float* __restrict__ r,
                      const float* __restrict__ Wc, const float* __restrict__ bc,
                      float* __restrict__ out) {
    __shared__ float red0[16], red1[16];
    int t = threadIdx.x;
    float c0 = 0.f, c1 = 0.f;
    for (int n = t; n < NN; n += 1024) {
        float rv = r[n];
        c0 += rv * Wc[2 * n];
        c1 += rv * Wc[2 * n + 1];
    }
    #pragma unroll
    for (int off = 32; off > 0; off >>= 1) {
        c0 += __shfl_down(c0, off);
        c1 += __shfl_down(c1, off);
    }
    if ((t & 63) == 0) { red0[t >> 6] = c0; red1[t >> 6] = c1; }
    __syncthreads();
    if (t == 0) {
        float s0 = bc[0], s1 = bc[1];
        #pragma unroll
        for (int i = 0; i < 16; i++) { s0 += red0[i]; s1 += red1[i]; }
        out[0] = s0;
        out[1] = s1;
    }
}

// ---------------- launch ----------------

extern "C" void kernel_launch(void* const* d_in, const int* in_sizes, int n_in,
                              void* d_out, int out_size, void* d_ws, size_t ws_size,
                              hipStream_t stream) {
    MegaP p;
    p.x   = (const float*)d_in[0];
    p.ei  = (const int*)d_in[1];
    p.W1  = (const float*)d_in[2];
    p.as1 = (const float*)d_in[3];
    p.ad1 = (const float*)d_in[4];
    p.b1  = (const float*)d_in[5];
    p.W2  = (const float*)d_in[6];
    p.as2 = (const float*)d_in[7];
    p.ad2 = (const float*)d_in[8];
    p.b2  = (const float*)d_in[9];
    p.Wr  = (const float*)d_in[10];
    p.br  = (const float*)d_in[11];
    p.Wc  = (const float*)d_in[12];
    p.bc  = (const float*)d_in[13];
    p.out = (float*)d_out;

    float* h     = (float*)d_ws;                 // NN*HD
    float* g1    = h + (size_t)NN * HD;          // NN*HD
    float* a_s   = g1 + (size_t)NN * HD;         // NN
    float* a_d   = a_s + NN;                     // NN
    float* r     = a_d + NN;                     // NN
    int* counts  = (int*)(r + NN);               // NN
    int* offsets = counts + NN;                  // NN+1
    int* rank    = offsets + NN + 1;             // ET
    int* srclist = rank + ET;                    // ET
    p.h = h; p.g1 = g1; p.a_s = a_s; p.a_d = a_d; p.r = r;
    p.counts = counts; p.offsets = offsets; p.rank = rank; p.srclist = srclist;

    // ---- try cooperative mega-kernel (1024 blocks, then 512) ----
    void* kp[] = { &p };
    hipError_t e = hipLaunchCooperativeKernel((const void*)k_mega, dim3(1024),
                                              dim3(NTHR), kp, 0, stream);
    if (e != hipSuccess) {
        (void)hipGetLastError();
        e = hipLaunchCooperativeKernel((const void*)k_mega, dim3(512),
                                       dim3(NTHR), kp, 0, stream);
    }
    if (e == hipSuccess) return;
    (void)hipGetLastError();

    // ---- fallback: proven round-4 multi-kernel path ----
    const int GHIST = (ET + 255) / 256;
    hipMemsetAsync(counts, 0, NN * sizeof(int), stream);
    k_gemm1_hist<<<GB1 + GHIST, 256, 0, stream>>>(p.x, p.W1, p.as1, p.ad1, h, a_s, a_d,
                                                  p.ei, counts, rank);
    k_scan<<<1, 1024, 0, stream>>>(counts, offsets);
    k_scatter<<<GHIST, 256, 0, stream>>>(p.ei, rank, offsets, srclist);
    k_agg1<<<NN, 128, 0, stream>>>(offsets, srclist, a_s, a_d,
                                   (const float4*)h, p.b1, g1);
    k_gemm2<<<GB1, 256, 0, stream>>>(g1, p.W2, p.as2, p.ad2, h, a_s, a_d);
    k_agg2<<<NN, 128, 0, stream>>>(offsets, srclist, a_s, a_d,
                                   (const float4*)h, p.b2, p.Wr, p.br, r);
    k_cls<<<1, 1024, 0, stream>>>(r, p.Wc, p.bc, p.out);
}

// Round 6
// 192.784 us; speedup vs baseline: 5.4666x; 5.4666x over previous
//
#include <hip/hip_runtime.h>

#define NN 10000
#define EE 320000
#define ET (EE + NN)      // 330000 edges incl self-loops
#define FIN 256
#define HD 128
#define NEG 0.2f

#define GB1 625                     // gemm1 blocks in fused K1 (NN/16)
#define GHIST ((ET + 255) / 256)    // 1290 hist blocks

// Inputs fp32, edge_index int32, OUTPUT fp32.
// HW law (rounds 3+5): NO device-scope fences / grid.sync mid-pipeline on MI355X —
// per-XCD L2s are non-coherent and every release/acquire is a full L2 flush storm.
// Kernel-launch boundaries are the cheap sync primitive here.

// ---------------- K1: gemm1 (blocks 0..624) fused with hist+rank (blocks 625..) --------

__global__ __launch_bounds__(256) void k_gemm1_hist(
        const float* __restrict__ x, const float* __restrict__ W,
        const float* __restrict__ atts, const float* __restrict__ attd,
        float* __restrict__ h, float* __restrict__ a_s, float* __restrict__ a_d,
        const int* __restrict__ ei, int* __restrict__ counts, int* __restrict__ rank) {
    __shared__ float xs[16 * FIN];   // 16 KB (unused by hist blocks)
    int t = threadIdx.x;

    if (blockIdx.x >= GB1) {
        int i = (blockIdx.x - GB1) * 256 + t;
        if (i < ET) {
            int d = (i < EE) ? ei[EE + i] : (i - EE);
            rank[i] = atomicAdd(&counts[d], 1);
        }
        return;
    }

    int m0 = blockIdx.x * 16;
    const float4* xv = (const float4*)(x + (size_t)m0 * FIN);
    float4* xsv = (float4*)xs;
    #pragma unroll
    for (int i = 0; i < 4; i++)
        xsv[t + 256 * i] = xv[t + 256 * i];
    __syncthreads();

    int g = t >> 6;
    int tt = t & 63;
    int f = tt * 2;
    const float* xg = xs + g * 4 * FIN;

    float2 acc[4];
    #pragma unroll
    for (int m = 0; m < 4; m++) acc[m] = make_float2(0.f, 0.f);

    for (int k = 0; k < FIN; k += 4) {
        float2 w0 = *(const float2*)&W[(k + 0) * HD + f];
        float2 w1 = *(const float2*)&W[(k + 1) * HD + f];
        float2 w2 = *(const float2*)&W[(k + 2) * HD + f];
        float2 w3 = *(const float2*)&W[(k + 3) * HD + f];
        #pragma unroll
        for (int m = 0; m < 4; m++) {
            float4 xk = *(const float4*)&xg[m * FIN + k];
            acc[m].x += xk.x * w0.x; acc[m].y += xk.x * w0.y;
            acc[m].x += xk.y * w1.x; acc[m].y += xk.y * w1.y;
            acc[m].x += xk.z * w2.x; acc[m].y += xk.z * w2.y;
            acc[m].x += xk.w * w3.x; acc[m].y += xk.w * w3.y;
        }
    }

    float2 ats = *(const float2*)&atts[f];
    float2 atd = *(const float2*)&attd[f];
    #pragma unroll
    for (int m = 0; m < 4; m++) {
        int node = m0 + g * 4 + m;
        *(float2*)&h[(size_t)node * HD + f] = acc[m];
        float vs = acc[m].x * ats.x + acc[m].y * ats.y;
        float vd = acc[m].x * atd.x + acc[m].y * atd.y;
        #pragma unroll
        for (int off = 32; off > 0; off >>= 1) {
            vs += __shfl_down(vs, off);
            vd += __shfl_down(vd, off);
        }
        if (tt == 0) { a_s[node] = vs; a_d[node] = vd; }
    }
}

// ---------------- scan: single 1024-thread block, counts -> offsets[NN+1] ----------------

__global__ __launch_bounds__(1024) void k_scan(const int* __restrict__ counts,
                                               int* __restrict__ offsets) {
    const int CHUNK = 10;
    __shared__ int wsum[16];
    int t = threadIdx.x, lane = t & 63, wid = t >> 6;
    int base = t * CHUNK;
    int c[CHUNK];
    int s = 0;
    #pragma unroll
    for (int i = 0; i < CHUNK; i++) {
        int idx = base + i;
        c[i] = (idx < NN) ? counts[idx] : 0;
        s += c[i];
    }
    int ps = s;
    #pragma unroll
    for (int off = 1; off < 64; off <<= 1) {
        int v = __shfl_up(ps, off);
        if (lane >= off) ps += v;
    }
    if (lane == 63) wsum[wid] = ps;
    __syncthreads();
    if (t < 16) {
        int v = wsum[t];
        #pragma unroll
        for (int off = 1; off < 16; off <<= 1) {
            int u = __shfl_up(v, off);
            if (t >= off) v += u;
        }
        wsum[t] = v;
    }
    __syncthreads();
    int wbase = (wid > 0) ? wsum[wid - 1] : 0;
    int run = wbase + ps - s;
    #pragma unroll
    for (int i = 0; i < CHUNK; i++) {
        int idx = base + i;
        if (idx < NN) { offsets[idx] = run; run += c[i]; }
    }
    if (t == 1023) offsets[NN] = wbase + ps;
}

// ---------------- scatter: atomic-free, position = offsets[dst] + rank ----------------

__global__ __launch_bounds__(256) void k_scatter(const int* __restrict__ ei,
                                                 const int* __restrict__ rank,
                                                 const int* __restrict__ offsets,
                                                 int* __restrict__ srclist) {
    int i = blockIdx.x * blockDim.x + threadIdx.x;
    if (i >= ET) return;
    int s, d;
    if (i < EE) { s = ei[i]; d = ei[EE + i]; }
    else        { s = i - EE; d = s; }
    srclist[offsets[d] + rank[i]] = s;
}

// ---------------- aggregation: block per dst node, 8 edge-slots x 32 lanes ------------
// vs round-4 (4 slots): serial dependent-gather chain per slot halves (~4 edges/slot),
// 2x independent gathers in flight per block. Latency-bound regime fix.

__device__ __forceinline__ float edge_w(float as_v, float adn) {
    float e = as_v + adn;
    e = (e > 0.f) ? e : NEG * e;
    return __expf(e);
}

__global__ __launch_bounds__(256) void k_agg1(const int* __restrict__ offsets,
                       const int* __restrict__ srclist,
                       const float* __restrict__ a_s,
                       const float* __restrict__ a_d,
                       const float4* __restrict__ h4,
                       const float* __restrict__ bias,
                       float* __restrict__ g) {
    __shared__ float accs[8][HD];
    __shared__ float zs[8];
    int node = blockIdx.x;
    int t = threadIdx.x;
    int slot = t >> 5, q = t & 31;         // 8 slots x 32 lanes
    int beg = offsets[node], end = offsets[node + 1];
    float adn = a_d[node];
    float4 acc = make_float4(0.f, 0.f, 0.f, 0.f);
    float z = 0.f;
    int p = beg + slot;
    for (; p + 8 < end; p += 16) {
        int s0 = srclist[p];
        int s1 = srclist[p + 8];
        float4 h0 = h4[(size_t)s0 * 32 + q];
        float4 h1 = h4[(size_t)s1 * 32 + q];
        float w0 = edge_w(a_s[s0], adn);
        float w1 = edge_w(a_s[s1], adn);
        z += w0 + w1;
        acc.x += w0 * h0.x + w1 * h1.x;
        acc.y += w0 * h0.y + w1 * h1.y;
        acc.z += w0 * h0.z + w1 * h1.z;
        acc.w += w0 * h0.w + w1 * h1.w;
    }
    if (p < end) {
        int s0 = srclist[p];
        float4 h0 = h4[(size_t)s0 * 32 + q];
        float w0 = edge_w(a_s[s0], adn);
        z += w0;
        acc.x += w0 * h0.x; acc.y += w0 * h0.y;
        acc.z += w0 * h0.z; acc.w += w0 * h0.w;
    }
    *(float4*)&accs[slot][q * 4] = acc;
    if (q == 0) zs[slot] = z;
    __syncthreads();
    if (t < HD) {
        float v = accs[0][t] + accs[1][t] + accs[2][t] + accs[3][t]
                + accs[4][t] + accs[5][t] + accs[6][t] + accs[7][t];
        float zz = (zs[0] + zs[1] + zs[2] + zs[3])
                 + (zs[4] + zs[5] + zs[6] + zs[7]);
        float o = v / zz + bias[t];
        g[(size_t)node * HD + t] = (o > 0.f) ? o : 0.f;   // relu
    }
}

// ---------------- GEMM layer 2: h = g1 @ W2 (K=128) ----------------

__global__ __launch_bounds__(256) void k_gemm2(const float* __restrict__ x,
                        const float* __restrict__ W,
                        const float* __restrict__ atts,
                        const float* __restrict__ attd,
                        float* __restrict__ h,
                        float* __restrict__ a_s,
                        float* __restrict__ a_d) {
    __shared__ float xs[16 * HD];
    int t = threadIdx.x;
    int m0 = blockIdx.x * 16;
    const float4* xv = (const float4*)(x + (size_t)m0 * HD);
    float4* xsv = (float4*)xs;
    #pragma unroll
    for (int i = 0; i < 2; i++)
        xsv[t + 256 * i] = xv[t + 256 * i];
    __syncthreads();

    int g = t >> 6;
    int tt = t & 63;
    int f = tt * 2;
    const float* xg = xs + g * 4 * HD;

    float2 acc[4];
    #pragma unroll
    for (int m = 0; m < 4; m++) acc[m] = make_float2(0.f, 0.f);

    for (int k = 0; k < HD; k += 4) {
        float2 w0 = *(const float2*)&W[(k + 0) * HD + f];
        float2 w1 = *(const float2*)&W[(k + 1) * HD + f];
        float2 w2 = *(const float2*)&W[(k + 2) * HD + f];
        float2 w3 = *(const float2*)&W[(k + 3) * HD + f];
        #pragma unroll
        for (int m = 0; m < 4; m++) {
            float4 xk = *(const float4*)&xg[m * HD + k];
            acc[m].x += xk.x * w0.x; acc[m].y += xk.x * w0.y;
            acc[m].x += xk.y * w1.x; acc[m].y += xk.y * w1.y;
            acc[m].x += xk.z * w2.x; acc[m].y += xk.z * w2.y;
            acc[m].x += xk.w * w3.x; acc[m].y += xk.w * w3.y;
        }
    }

    float2 ats = *(const float2*)&atts[f];
    float2 atd = *(const float2*)&attd[f];
    #pragma unroll
    for (int m = 0; m < 4; m++) {
        int node = m0 + g * 4 + m;
        *(float2*)&h[(size_t)node * HD + f] = acc[m];
        float vs = acc[m].x * ats.x + acc[m].y * ats.y;
        float vd = acc[m].x * atd.x + acc[m].y * atd.y;
        #pragma unroll
        for (int off = 32; off > 0; off >>= 1) {
            vs += __shfl_down(vs, off);
            vd += __shfl_down(vd, off);
        }
        if (tt == 0) { a_s[node] = vs; a_d[node] = vd; }
    }
}

// ---------------- agg2 + reduce_dim fused: r[n] = relu(agg+b2) . Wr + br --------------

__global__ __launch_bounds__(256) void k_agg2(const int* __restrict__ offsets,
                       const int* __restrict__ srclist,
                       const float* __restrict__ a_s,
                       const float* __restrict__ a_d,
                       const float4* __restrict__ h4,
                       const float* __restrict__ bias,
                       const float* __restrict__ Wr,
                       const float* __restrict__ br,
                       float* __restrict__ r) {
    __shared__ float accs[8][HD];
    __shared__ float zs[8];
    __shared__ float pr[HD];
    int node = blockIdx.x;
    int t = threadIdx.x;
    int slot = t >> 5, q = t & 31;
    int beg = offsets[node], end = offsets[node + 1];
    float adn = a_d[node];
    float4 acc = make_float4(0.f, 0.f, 0.f, 0.f);
    float z = 0.f;
    int p = beg + slot;
    for (; p + 8 < end; p += 16) {
        int s0 = srclist[p];
        int s1 = srclist[p + 8];
        float4 h0 = h4[(size_t)s0 * 32 + q];
        float4 h1 = h4[(size_t)s1 * 32 + q];
        float w0 = edge_w(a_s[s0], adn);
        float w1 = edge_w(a_s[s1], adn);
        z += w0 + w1;
        acc.x += w0 * h0.x + w1 * h1.x;
        acc.y += w0 * h0.y + w1 * h1.y;
        acc.z += w0 * h0.z + w1 * h1.z;
        acc.w += w0 * h0.w + w1 * h1.w;
    }
    if (p < end) {
        int s0 = srclist[p];
        float4 h0 = h4[(size_t)s0 * 32 + q];
        float w0 = edge_w(a_s[s0], adn);
        z += w0;
        acc.x += w0 * h0.x; acc.y += w0 * h0.y;
        acc.z += w0 * h0.z; acc.w += w0 * h0.w;
    }
    *(float4*)&accs[slot][q * 4] = acc;
    if (q == 0) zs[slot] = z;
    __syncthreads();
    if (t < HD) {
        float v = accs[0][t] + accs[1][t] + accs[2][t] + accs[3][t]
                + accs[4][t] + accs[5][t] + accs[6][t] + accs[7][t];
        float zz = (zs[0] + zs[1] + zs[2] + zs[3])
                 + (zs[4] + zs[5] + zs[6] + zs[7]);
        float o = v / zz + bias[t];
        o = (o > 0.f) ? o : 0.f;
        pr[t] = o * Wr[t];
    }
    __syncthreads();
    if (t < 64) {
        float part = pr[t] + pr[t + 64];
        #pragma unroll
        for (int off = 32; off > 0; off >>= 1) part += __shfl_down(part, off);
        if (t == 0) r[node] = part + br[0];
    }
}

// ---------------- classifier: out[c] = sum_n r[n]*Wc[n,c] + bc[c] ----------------

__global__ __launch_bounds__(1024) void k_cls(const float* __restrict__ r,
                      const float* __restrict__ Wc,
                      const float* __restrict__ bc,
                      float* __restrict__ out) {
    __shared__ float red0[16], red1[16];
    int t = threadIdx.x;
    float c0 = 0.f, c1 = 0.f;
    for (int n = t; n < NN; n += 1024) {
        float rv = r[n];
        c0 += rv * Wc[2 * n];
        c1 += rv * Wc[2 * n + 1];
    }
    #pragma unroll
    for (int off = 32; off > 0; off >>= 1) {
        c0 += __shfl_down(c0, off);
        c1 += __shfl_down(c1, off);
    }
    if ((t & 63) == 0) { red0[t >> 6] = c0; red1[t >> 6] = c1; }
    __syncthreads();
    if (t == 0) {
        float s0 = bc[0], s1 = bc[1];
        #pragma unroll
        for (int i = 0; i < 16; i++) { s0 += red0[i]; s1 += red1[i]; }
        out[0] = s0;
        out[1] = s1;
    }
}

// ---------------- launch ----------------

extern "C" void kernel_launch(void* const* d_in, const int* in_sizes, int n_in,
                              void* d_out, int out_size, void* d_ws, size_t ws_size,
                              hipStream_t stream) {
    const float* x    = (const float*)d_in[0];
    const int*   ei   = (const int*)d_in[1];
    const float* W1   = (const float*)d_in[2];
    const float* as1  = (const float*)d_in[3];
    const float* ad1  = (const float*)d_in[4];
    const float* b1   = (const float*)d_in[5];
    const float* W2   = (const float*)d_in[6];
    const float* as2  = (const float*)d_in[7];
    const float* ad2  = (const float*)d_in[8];
    const float* b2   = (const float*)d_in[9];
    const float* Wr   = (const float*)d_in[10];
    const float* br   = (const float*)d_in[11];
    const float* Wc   = (const float*)d_in[12];
    const float* bc   = (const float*)d_in[13];
    float* out = (float*)d_out;

    // workspace layout
    float* h     = (float*)d_ws;                 // NN*HD
    float* g1    = h + (size_t)NN * HD;          // NN*HD
    float* a_s   = g1 + (size_t)NN * HD;         // NN
    float* a_d   = a_s + NN;                     // NN
    float* r     = a_d + NN;                     // NN
    int* counts  = (int*)(r + NN);               // NN
    int* offsets = counts + NN;                  // NN+1
    int* rank    = offsets + NN + 1;             // ET
    int* srclist = rank + ET;                    // ET

    hipMemsetAsync(counts, 0, NN * sizeof(int), stream);

    k_gemm1_hist<<<GB1 + GHIST, 256, 0, stream>>>(x, W1, as1, ad1, h, a_s, a_d,
                                                  ei, counts, rank);
    k_scan<<<1, 1024, 0, stream>>>(counts, offsets);
    k_scatter<<<GHIST, 256, 0, stream>>>(ei, rank, offsets, srclist);

    k_agg1<<<NN, 256, 0, stream>>>(offsets, srclist, a_s, a_d,
                                   (const float4*)h, b1, g1);
    k_gemm2<<<GB1, 256, 0, stream>>>(g1, W2, as2, ad2, h, a_s, a_d);
    k_agg2<<<NN, 256, 0, stream>>>(offsets, srclist, a_s, a_d,
                                   (const float4*)h, b2, Wr, br, r);
    k_cls<<<1, 1024, 0, stream>>>(r, Wc, bc, out);
}

// Round 7
// 179.673 us; speedup vs baseline: 5.8655x; 1.0730x over previous
//
#include <hip/hip_runtime.h>

#define NN 10000
#define EE 320000
#define ET (EE + NN)      // 330000 edges incl self-loops
#define FIN 256
#define HD 128
#define NEG 0.2f
#define CAPS 7            // log2 bucket capacity
#define CAP (1 << CAPS)   // 128 slots/node; max degree ~Poisson(32)+1 << 128

#define GB1 625                     // gemm1 blocks in fused K1 (NN/16)
#define GSC ((ET + 255) / 256)      // 1290 scatter blocks

// Inputs fp32, edge_index int32, OUTPUT fp32.
// HW law (rounds 3+5): NO device-scope fences / grid.sync mid-pipeline on MI355X —
// per-XCD L2s are non-coherent; every release/acquire is an L2 flush storm
// (fence pattern: 230 µs; grid.sync x7: 978 µs). Kernel-launch boundaries are
// the cheap sync primitive. Round 6: aggs are NOT latency-chain-bound (8-slot = 4-slot).
// This round: padded buckets kill the scan + standalone scatter (8 -> 6 dispatches).

// ---------------- K1: gemm1 (blocks 0..624) || bucket-scatter (blocks 625..) ----------
// scatter: pos = atomicAdd(counts[d]); srclist[d*128+pos] = src. No scan, no offsets,
// no rank array. Atomic+store latency hides under the GEMM blocks' compute.

__global__ __launch_bounds__(256) void k_gemm1_scatter(
        const float* __restrict__ x, const float* __restrict__ W,
        const float* __restrict__ atts, const float* __restrict__ attd,
        float* __restrict__ h, float* __restrict__ a_s, float* __restrict__ a_d,
        const int* __restrict__ ei, int* __restrict__ counts, int* __restrict__ srclist) {
    __shared__ float xs[16 * FIN];   // 16 KB (unused by scatter blocks)
    int t = threadIdx.x;

    if (blockIdx.x >= GB1) {
        int i = (blockIdx.x - GB1) * 256 + t;
        if (i < ET) {
            int s, d;
            if (i < EE) { s = ei[i]; d = ei[EE + i]; }
            else        { s = i - EE; d = s; }
            int pos = atomicAdd(&counts[d], 1);
            srclist[(d << CAPS) + pos] = s;
        }
        return;
    }

    int m0 = blockIdx.x * 16;
    const float4* xv = (const float4*)(x + (size_t)m0 * FIN);
    float4* xsv = (float4*)xs;
    #pragma unroll
    for (int i = 0; i < 4; i++)      // 16*256/4 = 1024 float4 / 256 threads
        xsv[t + 256 * i] = xv[t + 256 * i];
    __syncthreads();

    int g = t >> 6;
    int tt = t & 63;
    int f = tt * 2;
    const float* xg = xs + g * 4 * FIN;

    float2 acc[4];
    #pragma unroll
    for (int m = 0; m < 4; m++) acc[m] = make_float2(0.f, 0.f);

    for (int k = 0; k < FIN; k += 4) {
        float2 w0 = *(const float2*)&W[(k + 0) * HD + f];
        float2 w1 = *(const float2*)&W[(k + 1) * HD + f];
        float2 w2 = *(const float2*)&W[(k + 2) * HD + f];
        float2 w3 = *(const float2*)&W[(k + 3) * HD + f];
        #pragma unroll
        for (int m = 0; m < 4; m++) {
            float4 xk = *(const float4*)&xg[m * FIN + k];
            acc[m].x += xk.x * w0.x; acc[m].y += xk.x * w0.y;
            acc[m].x += xk.y * w1.x; acc[m].y += xk.y * w1.y;
            acc[m].x += xk.z * w2.x; acc[m].y += xk.z * w2.y;
            acc[m].x += xk.w * w3.x; acc[m].y += xk.w * w3.y;
        }
    }

    float2 ats = *(const float2*)&atts[f];
    float2 atd = *(const float2*)&attd[f];
    #pragma unroll
    for (int m = 0; m < 4; m++) {
        int node = m0 + g * 4 + m;
        *(float2*)&h[(size_t)node * HD + f] = acc[m];
        float vs = acc[m].x * ats.x + acc[m].y * ats.y;
        float vd = acc[m].x * atd.x + acc[m].y * atd.y;
        #pragma unroll
        for (int off = 32; off > 0; off >>= 1) {
            vs += __shfl_down(vs, off);
            vd += __shfl_down(vd, off);
        }
        if (tt == 0) { a_s[node] = vs; a_d[node] = vd; }
    }
}

// ---------------- aggregation: block per dst node, 4 slots x 32 lanes (r4-proven) -----
// reads bucket [node*128, node*128 + counts[node])

__device__ __forceinline__ float edge_w(float as_v, float adn) {
    float e = as_v + adn;
    e = (e > 0.f) ? e : NEG * e;
    return __expf(e);
}

__global__ void k_agg1(const int* __restrict__ counts,
                       const int* __restrict__ srclist,
                       const float* __restrict__ a_s,
                       const float* __restrict__ a_d,
                       const float4* __restrict__ h4,
                       const float* __restrict__ bias,
                       float* __restrict__ g) {
    __shared__ float accs[4][HD];
    __shared__ float zs[4];
    int node = blockIdx.x;
    int t = threadIdx.x;
    int slot = t >> 5, q = t & 31;
    int beg = node << CAPS;
    int end = beg + counts[node];
    float adn = a_d[node];
    float4 acc = make_float4(0.f, 0.f, 0.f, 0.f);
    float z = 0.f;
    int p = beg + slot;
    for (; p + 4 < end; p += 8) {
        int s0 = srclist[p];
        int s1 = srclist[p + 4];
        float4 h0 = h4[(size_t)s0 * 32 + q];
        float4 h1 = h4[(size_t)s1 * 32 + q];
        float w0 = edge_w(a_s[s0], adn);
        float w1 = edge_w(a_s[s1], adn);
        z += w0 + w1;
        acc.x += w0 * h0.x + w1 * h1.x;
        acc.y += w0 * h0.y + w1 * h1.y;
        acc.z += w0 * h0.z + w1 * h1.z;
        acc.w += w0 * h0.w + w1 * h1.w;
    }
    if (p < end) {
        int s0 = srclist[p];
        float4 h0 = h4[(size_t)s0 * 32 + q];
        float w0 = edge_w(a_s[s0], adn);
        z += w0;
        acc.x += w0 * h0.x; acc.y += w0 * h0.y;
        acc.z += w0 * h0.z; acc.w += w0 * h0.w;
    }
    *(float4*)&accs[slot][q * 4] = acc;
    if (q == 0) zs[slot] = z;
    __syncthreads();
    float v = accs[0][t] + accs[1][t] + accs[2][t] + accs[3][t];
    float zz = zs[0] + zs[1] + zs[2] + zs[3];
    float o = v / zz + bias[t];
    g[(size_t)node * HD + t] = (o > 0.f) ? o : 0.f;   // relu
}

// ---------------- GEMM layer 2: h = g1 @ W2 (K=128) ----------------

__global__ __launch_bounds__(256) void k_gemm2(const float* __restrict__ x,
                        const float* __restrict__ W,
                        const float* __restrict__ atts,
                        const float* __restrict__ attd,
                        float* __restrict__ h,
                        float* __restrict__ a_s,
                        float* __restrict__ a_d) {
    __shared__ float xs[16 * HD];
    int t = threadIdx.x;
    int m0 = blockIdx.x * 16;
    const float4* xv = (const float4*)(x + (size_t)m0 * HD);
    float4* xsv = (float4*)xs;
    #pragma unroll
    for (int i = 0; i < 2; i++)
        xsv[t + 256 * i] = xv[t + 256 * i];
    __syncthreads();

    int g = t >> 6;
    int tt = t & 63;
    int f = tt * 2;
    const float* xg = xs + g * 4 * HD;

    float2 acc[4];
    #pragma unroll
    for (int m = 0; m < 4; m++) acc[m] = make_float2(0.f, 0.f);

    for (int k = 0; k < HD; k += 4) {
        float2 w0 = *(const float2*)&W[(k + 0) * HD + f];
        float2 w1 = *(const float2*)&W[(k + 1) * HD + f];
        float2 w2 = *(const float2*)&W[(k + 2) * HD + f];
        float2 w3 = *(const float2*)&W[(k + 3) * HD + f];
        #pragma unroll
        for (int m = 0; m < 4; m++) {
            float4 xk = *(const float4*)&xg[m * HD + k];
            acc[m].x += xk.x * w0.x; acc[m].y += xk.x * w0.y;
            acc[m].x += xk.y * w1.x; acc[m].y += xk.y * w1.y;
            acc[m].x += xk.z * w2.x; acc[m].y += xk.z * w2.y;
            acc[m].x += xk.w * w3.x; acc[m].y += xk.w * w3.y;
        }
    }

    float2 ats = *(const float2*)&atts[f];
    float2 atd = *(const float2*)&attd[f];
    #pragma unroll
    for (int m = 0; m < 4; m++) {
        int node = m0 + g * 4 + m;
        *(float2*)&h[(size_t)node * HD + f] = acc[m];
        float vs = acc[m].x * ats.x + acc[m].y * ats.y;
        float vd = acc[m].x * atd.x + acc[m].y * atd.y;
        #pragma unroll
        for (int off = 32; off > 0; off >>= 1) {
            vs += __shfl_down(vs, off);
            vd += __shfl_down(vd, off);
        }
        if (tt == 0) { a_s[node] = vs; a_d[node] = vd; }
    }
}

// ---------------- agg2 + reduce_dim fused: r[n] = relu(agg+b2) . Wr + br --------------

__global__ void k_agg2(const int* __restrict__ counts,
                       const int* __restrict__ srclist,
                       const float* __restrict__ a_s,
                       const float* __restrict__ a_d,
                       const float4* __restrict__ h4,
                       const float* __restrict__ bias,
                       const float* __restrict__ Wr,
                       const float* __restrict__ br,
                       float* __restrict__ r) {
    __shared__ float accs[4][HD];
    __shared__ float zs[4];
    __shared__ float red[2];
    int node = blockIdx.x;
    int t = threadIdx.x;
    int slot = t >> 5, q = t & 31;
    int beg = node << CAPS;
    int end = beg + counts[node];
    float adn = a_d[node];
    float4 acc = make_float4(0.f, 0.f, 0.f, 0.f);
    float z = 0.f;
    int p = beg + slot;
    for (; p + 4 < end; p += 8) {
        int s0 = srclist[p];
        int s1 = srclist[p + 4];
        float4 h0 = h4[(size_t)s0 * 32 + q];
        float4 h1 = h4[(size_t)s1 * 32 + q];
        float w0 = edge_w(a_s[s0], adn);
        float w1 = edge_w(a_s[s1], adn);
        z += w0 + w1;
        acc.x += w0 * h0.x + w1 * h1.x;
        acc.y += w0 * h0.y + w1 * h1.y;
        acc.z += w0 * h0.z + w1 * h1.z;
        acc.w += w0 * h0.w + w1 * h1.w;
    }
    if (p < end) {
        int s0 = srclist[p];
        float4 h0 = h4[(size_t)s0 * 32 + q];
        float w0 = edge_w(a_s[s0], adn);
        z += w0;
        acc.x += w0 * h0.x; acc.y += w0 * h0.y;
        acc.z += w0 * h0.z; acc.w += w0 * h0.w;
    }
    *(float4*)&accs[slot][q * 4] = acc;
    if (q == 0) zs[slot] = z;
    __syncthreads();
    float v = accs[0][t] + accs[1][t] + accs[2][t] + accs[3][t];
    float zz = zs[0] + zs[1] + zs[2] + zs[3];
    float o = v / zz + bias[t];
    o = (o > 0.f) ? o : 0.f;
    float part = o * Wr[t];
    #pragma unroll
    for (int off = 32; off > 0; off >>= 1) part += __shfl_down(part, off);
    if ((t & 63) == 0) red[t >> 6] = part;
    __syncthreads();
    if (t == 0) r[node] = red[0] + red[1] + br[0];
}

// ---------------- classifier: out[c] = sum_n r[n]*Wc[n,c] + bc[c] ----------------

__global__ __launch_bounds__(1024) void k_cls(const float* __restrict__ r,
                      const float* __restrict__ Wc,
                      const float* __restrict__ bc,
                      float* __restrict__ out) {
    __shared__ float red0[16], red1[16];
    int t = threadIdx.x;
    float c0 = 0.f, c1 = 0.f;
    for (int n = t; n < NN; n += 1024) {
        float rv = r[n];
        c0 += rv * Wc[2 * n];
        c1 += rv * Wc[2 * n + 1];
    }
    #pragma unroll
    for (int off = 32; off > 0; off >>= 1) {
        c0 += __shfl_down(c0, off);
        c1 += __shfl_down(c1, off);
    }
    if ((t & 63) == 0) { red0[t >> 6] = c0; red1[t >> 6] = c1; }
    __syncthreads();
    if (t == 0) {
        float s0 = bc[0], s1 = bc[1];
        #pragma unroll
        for (int i = 0; i < 16; i++) { s0 += red0[i]; s1 += red1[i]; }
        out[0] = s0;
        out[1] = s1;
    }
}

// ---------------- launch: 6 dispatches, all boundaries are true data deps -------------

extern "C" void kernel_launch(void* const* d_in, const int* in_sizes, int n_in,
                              void* d_out, int out_size, void* d_ws, size_t ws_size,
                              hipStream_t stream) {
    const float* x    = (const float*)d_in[0];
    const int*   ei   = (const int*)d_in[1];
    const float* W1   = (const float*)d_in[2];
    const float* as1  = (const float*)d_in[3];
    const float* ad1  = (const float*)d_in[4];
    const float* b1   = (const float*)d_in[5];
    const float* W2   = (const float*)d_in[6];
    const float* as2  = (const float*)d_in[7];
    const float* ad2  = (const float*)d_in[8];
    const float* b2   = (const float*)d_in[9];
    const float* Wr   = (const float*)d_in[10];
    const float* br   = (const float*)d_in[11];
    const float* Wc   = (const float*)d_in[12];
    const float* bc   = (const float*)d_in[13];
    float* out = (float*)d_out;

    // workspace layout
    float* h     = (float*)d_ws;                 // NN*HD
    float* g1    = h + (size_t)NN * HD;          // NN*HD
    float* a_s   = g1 + (size_t)NN * HD;         // NN
    float* a_d   = a_s + NN;                     // NN
    float* r     = a_d + NN;                     // NN
    int* counts  = (int*)(r + NN);               // NN
    int* srclist = counts + NN;                  // NN*CAP (5.12 MB)

    hipMemsetAsync(counts, 0, NN * sizeof(int), stream);

    // K1: gemm1 || bucket-scatter
    k_gemm1_scatter<<<GB1 + GSC, 256, 0, stream>>>(x, W1, as1, ad1, h, a_s, a_d,
                                                   ei, counts, srclist);
    // layer 1 aggregation
    k_agg1<<<NN, 128, 0, stream>>>(counts, srclist, a_s, a_d,
                                   (const float4*)h, b1, g1);
    // layer 2
    k_gemm2<<<GB1, 256, 0, stream>>>(g1, W2, as2, ad2, h, a_s, a_d);
    k_agg2<<<NN, 128, 0, stream>>>(counts, srclist, a_s, a_d,
                                   (const float4*)h, b2, Wr, br, r);
    // classifier
    k_cls<<<1, 1024, 0, stream>>>(r, Wc, bc, out);
}